// Round 10
// baseline (368.826 us; speedup 1.0000x reference)
//
#include <hip/hip_runtime.h>
#include <hip/hip_bf16.h>

// ---------------------------------------------------------------------------
// InfiniAttention on MI355X — round 10 (= round-8 kernel, two timeouts, never
// benched). R7 baseline: attn 82us latency-bound at 2 waves/SIMD.
// This round: attn KV-split (h, qt, half) 512 blocks x 512 thr, 80KB LDS ->
//     16 waves/CU; defer-max; merge+mem-path in combine kernel; qk epilogue
//     writes vT/skT directly (transpose_b2b dispatches removed).
// ---------------------------------------------------------------------------

#define S_LEN 2048
#define HID 2048
#define NH 16
#define HD 128
#define SCALE_QK 0.088388347648318447f

typedef __attribute__((ext_vector_type(8))) short bf16x8;
typedef __attribute__((ext_vector_type(4))) float f32x4;

__device__ __forceinline__ short f2bf(float f) {
  __hip_bfloat16 h = __float2bfloat16(f);
  return __builtin_bit_cast(short, h);
}
__device__ __forceinline__ float bf2f(short s) {
  unsigned int u = ((unsigned int)(unsigned short)s) << 16;
  return __builtin_bit_cast(float, u);
}
__device__ __forceinline__ void gload16(const void* g, void* l) {
  __builtin_amdgcn_global_load_lds(
      (const __attribute__((address_space(1))) void*)g,
      (__attribute__((address_space(3))) void*)l, 16, 0, 0);
}

// --------------------------- elementwise convert ---------------------------
__global__ __launch_bounds__(256) void f32_to_bf16_kernel(
    const float* __restrict__ in, short* __restrict__ out) {
  size_t i = (size_t)(blockIdx.x * 256 + threadIdx.x) * 8;
  float4 a = *reinterpret_cast<const float4*>(in + i);
  float4 b = *reinterpret_cast<const float4*>(in + i + 4);
  alignas(16) short t[8] = {f2bf(a.x), f2bf(a.y), f2bf(a.z), f2bf(a.w),
                            f2bf(b.x), f2bf(b.y), f2bf(b.z), f2bf(b.w)};
  *reinterpret_cast<int4*>(out + i) = *reinterpret_cast<int4*>(t);
}

// --------------------------- transposes ------------------------------------
__global__ __launch_bounds__(256) void transpose_f2b_kernel(
    const float* __restrict__ in, short* __restrict__ out, int R, int C) {
  __shared__ float t[32][33];
  size_t bo = (size_t)blockIdx.z * R * C;
  int r0 = blockIdx.y * 32, c0 = blockIdx.x * 32;
  int tx = threadIdx.x & 31, ty = threadIdx.x >> 5;
#pragma unroll
  for (int i = 0; i < 4; ++i)
    t[ty + i * 8][tx] = in[bo + (size_t)(r0 + ty + i * 8) * C + c0 + tx];
  __syncthreads();
#pragma unroll
  for (int i = 0; i < 4; ++i)
    out[bo + (size_t)(c0 + ty + i * 8) * R + r0 + tx] = f2bf(t[tx][ty + i * 8]);
}

// --------------------------- rope tables -----------------------------------
__global__ __launch_bounds__(256) void tables_kernel(
    const int* __restrict__ pos_ids, float* __restrict__ cost,
    float* __restrict__ sint) {
  int idx = blockIdx.x * 256 + threadIdx.x;
  int s = idx >> 6, j = idx & 63;
  float pos = (float)pos_ids[s];
  float inv = powf(10000.0f, -((float)j) / 64.0f);
  float a = pos * inv;
  cost[idx] = cosf(a);
  sint[idx] = sinf(a);
}

// ------------- fused qk GEMM + rope/elu + direct vT/skT ---------------------
__global__ __launch_bounds__(256) void gemm_qk_rope_kernel(
    const short* __restrict__ A, const short* __restrict__ BT,
    const float* __restrict__ bq, const float* __restrict__ bk,
    const float* __restrict__ cost, const float* __restrict__ sint,
    short* __restrict__ qr, short* __restrict__ kr, short* __restrict__ sq,
    short* __restrict__ skT, short* __restrict__ vT) {
  __shared__ __align__(16) char smem[67584];  // dbuf 64KB / qbuf 128x132 f32
  const int tid = threadIdx.x;
  const int wave = tid >> 6, lane = tid & 63;
  const int g = lane >> 4, l15 = lane & 15;
  const int wm = (wave >> 1) * 64, wn = (wave & 1) * 64;
  const int row0 = blockIdx.x * 128;
  const int colg0 = blockIdx.y * 128;

  const int ld_r = wave * 32 + (lane >> 3);
  const int ld_c = (lane & 7) * 8;
  const short* Ag = A + (size_t)(row0 + ld_r) * 2048 + ld_c;
  const short* Bg = BT + (size_t)(colg0 + ld_r) * 2048 + ld_c;

#define GSTAGE(BUF, KT)                                                       \
  {                                                                           \
    _Pragma("unroll") for (int i = 0; i < 4; ++i) {                           \
      gload16(Ag + (size_t)(KT) * 64 + (size_t)i * 8 * 2048,                  \
              smem + (BUF) * 32768 + wave * 4096 + i * 1024);                 \
      gload16(Bg + (size_t)(KT) * 64 + (size_t)i * 8 * 2048,                  \
              smem + (BUF) * 32768 + 16384 + wave * 4096 + i * 1024);         \
    }                                                                         \
  }

  f32x4 acc[4][4] = {};
  GSTAGE(0, 0);
  __syncthreads();
  for (int kt = 0; kt < 32; ++kt) {
    const int cur = kt & 1;
    if (kt + 1 < 32) GSTAGE(cur ^ 1, kt + 1);
#pragma unroll
    for (int ks = 0; ks < 2; ++ks) {
      bf16x8 a[4], b[4];
#pragma unroll
      for (int m = 0; m < 4; ++m)
        a[m] = *reinterpret_cast<bf16x8*>(smem + cur * 32768 +
                                          (wm + m * 16 + l15) * 128 +
                                          (ks * 32 + g * 8) * 2);
#pragma unroll
      for (int n = 0; n < 4; ++n)
        b[n] = *reinterpret_cast<bf16x8*>(smem + cur * 32768 + 16384 +
                                          (wn + n * 16 + l15) * 128 +
                                          (ks * 32 + g * 8) * 2);
#pragma unroll
      for (int m = 0; m < 4; ++m)
#pragma unroll
        for (int n = 0; n < 4; ++n)
          acc[m][n] = __builtin_amdgcn_mfma_f32_16x16x32_bf16(a[m], b[n],
                                                              acc[m][n], 0, 0, 0);
    }
    __syncthreads();
  }
#undef GSTAGE

  const bool qpath = (colg0 < 2048);
  const int col0 = qpath ? colg0 : colg0 - 2048;
  const int hh = col0 >> 7;
  const float* bias = qpath ? bq : bk;
  float* qb = reinterpret_cast<float*>(smem);
#pragma unroll
  for (int m = 0; m < 4; ++m)
#pragma unroll
    for (int n = 0; n < 4; ++n) {
      int rl = wm + m * 16 + g * 4;
      int cl = wn + n * 16 + l15;
      float bv = bias[col0 + cl];
#pragma unroll
      for (int r = 0; r < 4; ++r) qb[(rl + r) * 132 + cl] = acc[m][n][r] + bv;
    }
  __syncthreads();

  // row-major outputs: qr,sq (qpath) / kr (kpath)
  {
    const int rl = tid >> 1;
    const int c0 = (tid & 1) * 64;
    const int rowg = row0 + rl;
    const float sgn = (c0 == 0) ? -1.0f : 1.0f;
    const size_t obase = (size_t)rowg * HID + col0 + c0;
#pragma unroll
    for (int j0 = 0; j0 < 64; j0 += 8) {
      alignas(16) short o1[8], o2[8];
#pragma unroll
      for (int jj = 0; jj < 8; ++jj) {
        int j = j0 + jj;
        float self = qb[rl * 132 + c0 + j];
        float part = qb[rl * 132 + (c0 ^ 64) + j];
        float cs = cost[rowg * 64 + j];
        float sn = sint[rowg * 64 + j];
        float rv = self * cs + sgn * part * sn;
        o1[jj] = f2bf(rv);
        o2[jj] = f2bf(rv > 0.0f ? rv + 1.0f : __expf(rv));
      }
      if (qpath) {
        *reinterpret_cast<int4*>(qr + obase + j0) = *reinterpret_cast<int4*>(o1);
        *reinterpret_cast<int4*>(sq + obase + j0) = *reinterpret_cast<int4*>(o2);
      } else {
        *reinterpret_cast<int4*>(kr + obase + j0) = *reinterpret_cast<int4*>(o1);
      }
    }
  }

  // transposed outputs: vT = pre-rope q (qpath) / skT = elu(rope(k)) (kpath)
  {
    const int d = tid & 127;
    const int sc = tid >> 7;
    const int dp = d ^ 64;
    const float sgn2 = (d < 64) ? -1.0f : 1.0f;
    short* dstb = (qpath ? vT : skT) + (size_t)(hh * HD + d) * S_LEN + row0 +
                  sc * 64;
#pragma unroll
    for (int j0 = 0; j0 < 64; j0 += 8) {
      alignas(16) short ot[8];
#pragma unroll
      for (int jj = 0; jj < 8; ++jj) {
        int s = sc * 64 + j0 + jj;
        float self = qb[s * 132 + d];
        if (qpath) {
          ot[jj] = f2bf(self);
        } else {
          float part = qb[s * 132 + dp];
          int rowg = row0 + s;
          float cs = cost[rowg * 64 + (d & 63)];
          float sn = sint[rowg * 64 + (d & 63)];
          float rv = self * cs + sgn2 * part * sn;
          ot[jj] = f2bf(rv > 0.0f ? rv + 1.0f : __expf(rv));
        }
      }
      *reinterpret_cast<int4*>(dstb + j0) = *reinterpret_cast<int4*>(ot);
    }
  }
}

// --------------- Wo GEMM (dbuf, 1 barrier/tile, f32 out) --------------------
__global__ __launch_bounds__(256) void gemm_wo_kernel(
    const short* __restrict__ A, const short* __restrict__ BT,
    float* __restrict__ C) {
  __shared__ __align__(16) char smem[65536];
  const int tid = threadIdx.x;
  const int wave = tid >> 6, lane = tid & 63;
  const int g = lane >> 4, l15 = lane & 15;
  const int wm = (wave >> 1) * 64, wn = (wave & 1) * 64;
  const int row0 = blockIdx.x * 128;
  const int col0 = blockIdx.y * 128;

  const int ld_r = wave * 32 + (lane >> 3);
  const int ld_c = (lane & 7) * 8;
  const short* Ag = A + (size_t)(row0 + ld_r) * 2048 + ld_c;
  const short* Bg = BT + (size_t)(col0 + ld_r) * 2048 + ld_c;

#define GSTAGE(BUF, KT)                                                       \
  {                                                                           \
    _Pragma("unroll") for (int i = 0; i < 4; ++i) {                           \
      gload16(Ag + (size_t)(KT) * 64 + (size_t)i * 8 * 2048,                  \
              smem + (BUF) * 32768 + wave * 4096 + i * 1024);                 \
      gload16(Bg + (size_t)(KT) * 64 + (size_t)i * 8 * 2048,                  \
              smem + (BUF) * 32768 + 16384 + wave * 4096 + i * 1024);         \
    }                                                                         \
  }

  f32x4 acc[4][4] = {};
  GSTAGE(0, 0);
  __syncthreads();
  for (int kt = 0; kt < 32; ++kt) {
    const int cur = kt & 1;
    if (kt + 1 < 32) GSTAGE(cur ^ 1, kt + 1);
#pragma unroll
    for (int ks = 0; ks < 2; ++ks) {
      bf16x8 a[4], b[4];
#pragma unroll
      for (int m = 0; m < 4; ++m)
        a[m] = *reinterpret_cast<bf16x8*>(smem + cur * 32768 +
                                          (wm + m * 16 + l15) * 128 +
                                          (ks * 32 + g * 8) * 2);
#pragma unroll
      for (int n = 0; n < 4; ++n)
        b[n] = *reinterpret_cast<bf16x8*>(smem + cur * 32768 + 16384 +
                                          (wn + n * 16 + l15) * 128 +
                                          (ks * 32 + g * 8) * 2);
#pragma unroll
      for (int m = 0; m < 4; ++m)
#pragma unroll
        for (int n = 0; n < 4; ++n)
          acc[m][n] = __builtin_amdgcn_mfma_f32_16x16x32_bf16(a[m], b[n],
                                                              acc[m][n], 0, 0, 0);
    }
    __syncthreads();
  }
#undef GSTAGE

#pragma unroll
  for (int m = 0; m < 4; ++m)
#pragma unroll
    for (int n = 0; n < 4; ++n) {
      int row = row0 + wm + m * 16 + g * 4;
      int col = col0 + wn + n * 16 + l15;
#pragma unroll
      for (int r = 0; r < 4; ++r)
        C[(size_t)(row + r) * 2048 + col] = acc[m][n][r];
    }
}

// --------------------------- flash attention (KV-split) ---------------------
// 512 blocks: h = bid&15, w = bid>>4; w<16: qt=w half=0 ; else qt=31-w half=1.
// 8 waves x 16 q-rows (QBLK=128). KVBLK=64 dbuf via gload_lds. 80KB LDS.
// Outputs unnormalized o (bf16) + per-row (m,l) f32 partials.
__global__ __launch_bounds__(512, 4) void attn_kernel(
    const short* __restrict__ qr, const short* __restrict__ kr,
    const short* __restrict__ vT, short* __restrict__ opart,
    float* __restrict__ ml) {
  __shared__ short k_s[2][64 * 128];  // 32KB [t][d] swizzled
  __shared__ short v_s[2][128 * 64];  // 32KB [d][t] swizzled
  __shared__ short p_s[8][16 * 64];   // 16KB per-wave [q][t]
  const int tid = threadIdx.x;
  const int wave = tid >> 6, lane = tid & 63;
  const int g = lane >> 4, l15 = lane & 15;
  const int bid = blockIdx.x;
  const int h = bid & 15;
  const int w = bid >> 4;
  const int half = (w < 16) ? 0 : 1;
  const int qt = (w < 16) ? w : 31 - w;
  const int q0 = qt * 128;
  const int jstart = half ? (qt + 1) : 0;
  const int jend = half ? (2 * qt + 2) : (qt + 1);

  const int krow_b = wave * 8 + (lane >> 4);
  const int vrow_b = wave * 16 + (lane >> 3);
#define STAGE_TILE(B, T0)                                                     \
  {                                                                           \
    _Pragma("unroll") for (int i = 0; i < 2; ++i) {                           \
      int rk = krow_b + i * 4;                                                \
      int ck = (lane & 15) ^ (rk & 7);                                        \
      gload16(kr + (size_t)((T0) + rk) * HID + h * HD + ck * 8,               \
              &k_s[B][0] + wave * 1024 + i * 512);                            \
      int rv = vrow_b + i * 8;                                                \
      int cv = (lane & 7) ^ (rv & 7);                                         \
      gload16(vT + (size_t)(h * HD + rv) * S_LEN + (T0) + cv * 8,             \
              &v_s[B][0] + wave * 1024 + i * 512);                            \
    }                                                                         \
  }

  bf16x8 qf[4];
#pragma unroll
  for (int ks = 0; ks < 4; ++ks) {
    int row = q0 + wave * 16 + l15;
    qf[ks] = *reinterpret_cast<const bf16x8*>(qr + (size_t)row * HID + h * HD +
                                              ks * 32 + g * 8);
  }

  STAGE_TILE(0, jstart * 64);
  __syncthreads();

  f32x4 o[8] = {};
  float m_run[4], l_run[4];
#pragma unroll
  for (int r = 0; r < 4; ++r) {
    m_run[r] = -3.0e38f;
    l_run[r] = 0.0f;
  }

  for (int j = jstart; j < jend; ++j) {
    const int cur = (j - jstart) & 1;
    if (j + 1 < jend) STAGE_TILE(cur ^ 1, (j + 1) * 64);

    f32x4 sfr[4] = {};
    __builtin_amdgcn_s_setprio(1);
#pragma unroll
    for (int n = 0; n < 4; ++n) {
#pragma unroll
      for (int ks = 0; ks < 4; ++ks) {
        int rr = n * 16 + l15;
        int off = (rr * 256 + (ks * 32 + g * 8) * 2) ^ ((rr & 7) << 4);
        bf16x8 b =
            *reinterpret_cast<bf16x8*>(reinterpret_cast<char*>(k_s[cur]) + off);
        sfr[n] = __builtin_amdgcn_mfma_f32_16x16x32_bf16(qf[ks], b, sfr[n], 0,
                                                         0, 0);
      }
    }
    __builtin_amdgcn_s_setprio(0);

    const bool diag = (j >= 2 * qt);
#pragma unroll
    for (int r = 0; r < 4; ++r) {
      const int srow = q0 + wave * 16 + g * 4 + r;
      float pmax = -3.0e38f;
#pragma unroll
      for (int n = 0; n < 4; ++n) {
        float val = sfr[n][r] * SCALE_QK;
        if (diag) {
          int t = j * 64 + n * 16 + l15;
          val = (t <= srow) ? val : -3.0e38f;
        }
        sfr[n][r] = val;
        pmax = fmaxf(pmax, val);
      }
      pmax = fmaxf(pmax, __shfl_xor(pmax, 1));
      pmax = fmaxf(pmax, __shfl_xor(pmax, 2));
      pmax = fmaxf(pmax, __shfl_xor(pmax, 4));
      pmax = fmaxf(pmax, __shfl_xor(pmax, 8));
      if (pmax > m_run[r] + 8.0f) {  // defer-max: rescale rarely fires
        float f = __expf(m_run[r] - pmax);
        l_run[r] *= f;
#pragma unroll
        for (int n = 0; n < 8; ++n) o[n][r] *= f;
        m_run[r] = pmax;
      }
      float sum = 0.0f;
#pragma unroll
      for (int n = 0; n < 4; ++n) {
        float p = __expf(sfr[n][r] - m_run[r]);
        sfr[n][r] = p;
        sum += p;
      }
      sum += __shfl_xor(sum, 1);
      sum += __shfl_xor(sum, 2);
      sum += __shfl_xor(sum, 4);
      sum += __shfl_xor(sum, 8);
      l_run[r] += sum;
    }

    char* pw = reinterpret_cast<char*>(p_s[wave]);
#pragma unroll
    for (int n = 0; n < 4; ++n)
#pragma unroll
      for (int r = 0; r < 4; ++r) {
        int rl = g * 4 + r;
        int off = (rl * 128 + (n * 16 + l15) * 2) ^ ((rl & 7) << 4);
        *reinterpret_cast<short*>(pw + off) = f2bf(sfr[n][r]);
      }

    __builtin_amdgcn_s_setprio(1);
#pragma unroll
    for (int ks = 0; ks < 2; ++ks) {
      int offp = (l15 * 128 + (ks * 32 + g * 8) * 2) ^ ((l15 & 7) << 4);
      bf16x8 pa = *reinterpret_cast<bf16x8*>(pw + offp);
#pragma unroll
      for (int n = 0; n < 8; ++n) {
        int rr = n * 16 + l15;
        int off = (rr * 128 + (ks * 32 + g * 8) * 2) ^ ((rr & 7) << 4);
        bf16x8 vb =
            *reinterpret_cast<bf16x8*>(reinterpret_cast<char*>(v_s[cur]) + off);
        o[n] = __builtin_amdgcn_mfma_f32_16x16x32_bf16(pa, vb, o[n], 0, 0, 0);
      }
    }
    __builtin_amdgcn_s_setprio(0);

    __syncthreads();
  }
#undef STAGE_TILE

  // epilogue: unnormalized o -> opart (bf16), (m,l) -> ml
  const size_t ob = (size_t)half * 4194304;
#pragma unroll
  for (int r = 0; r < 4; ++r) {
    int row = q0 + wave * 16 + g * 4 + r;
#pragma unroll
    for (int n = 0; n < 8; ++n) {
      int col = n * 16 + l15;
      opart[ob + (size_t)row * HID + h * HD + col] = f2bf(o[n][r]);
    }
    if (l15 == 0) {
      size_t mli = ((size_t)(half * 16 + h) * 2048 + row) * 2;
      ml[mli] = m_run[r];
      ml[mli + 1] = l_run[r];
    }
  }
}

// --------------- combine: merge halves + mem path + gate -------------------
__global__ __launch_bounds__(256) void combine_kernel(
    const short* __restrict__ opart, const float* __restrict__ ml,
    const short* __restrict__ sq, const short* __restrict__ MT,
    const float* __restrict__ z, const float* __restrict__ beta,
    short* __restrict__ comb) {
  __shared__ short mt_s[128 * 128];
  const int tid = threadIdx.x;
  const int wave = tid >> 6, lane = tid & 63;
  const int g = lane >> 4, l15 = lane & 15;
  const int h = blockIdx.y;
  const int s0 = blockIdx.x * 128;
#pragma unroll
  for (int i = 0; i < 8; ++i) {
    int c = tid + 256 * i;
    int r = c >> 4, kc = c & 15;
    int4 d = *reinterpret_cast<const int4*>(MT + (size_t)h * 16384 + r * 128 +
                                            kc * 8);
    *reinterpret_cast<int4*>(reinterpret_cast<char*>(mt_s) +
                             ((r * 256 + kc * 16) ^ ((r & 7) << 4))) = d;
  }
  __syncthreads();

  f32x4 acc[2][8] = {};
#pragma unroll
  for (int ks = 0; ks < 4; ++ks) {
    bf16x8 a[2];
#pragma unroll
    for (int m = 0; m < 2; ++m) {
      int row = s0 + wave * 32 + m * 16 + l15;
      a[m] = *reinterpret_cast<const bf16x8*>(sq + (size_t)row * HID + h * HD +
                                              ks * 32 + g * 8);
    }
#pragma unroll
    for (int n = 0; n < 8; ++n) {
      int rr = n * 16 + l15;
      int off = (rr * 256 + (ks * 32 + g * 8) * 2) ^ ((rr & 7) << 4);
      bf16x8 b = *reinterpret_cast<bf16x8*>(reinterpret_cast<char*>(mt_s) + off);
#pragma unroll
      for (int m = 0; m < 2; ++m)
        acc[m][n] =
            __builtin_amdgcn_mfma_f32_16x16x32_bf16(a[m], b, acc[m][n], 0, 0, 0);
    }
  }

  float den[2][4];
#pragma unroll
  for (int m = 0; m < 2; ++m)
#pragma unroll
    for (int r = 0; r < 4; ++r) {
      int row = s0 + wave * 32 + m * 16 + g * 4 + r;
      bf16x8 sv = *reinterpret_cast<const bf16x8*>(sq + (size_t)row * HID +
                                                   h * HD + l15 * 8);
      float part = 0.0f;
#pragma unroll
      for (int j = 0; j < 8; ++j) part += bf2f(sv[j]) * z[h * HD + l15 * 8 + j];
      part += __shfl_xor(part, 1);
      part += __shfl_xor(part, 2);
      part += __shfl_xor(part, 4);
      part += __shfl_xor(part, 8);
      den[m][r] = part + 1e-8f;
    }
  float gv = 1.0f / (1.0f + __expf(-beta[0]));
#pragma unroll
  for (int m = 0; m < 2; ++m)
#pragma unroll
    for (int r = 0; r < 4; ++r) {
      int row = s0 + wave * 32 + m * 16 + g * 4 + r;
      float m0 = ml[((size_t)h * 2048 + row) * 2];
      float l0 = ml[((size_t)h * 2048 + row) * 2 + 1];
      float m1 = ml[((size_t)(16 + h) * 2048 + row) * 2];
      float l1 = ml[((size_t)(16 + h) * 2048 + row) * 2 + 1];
      float mm = fmaxf(m0, m1);
      float e0 = __expf(m0 - mm), e1 = __expf(m1 - mm);
      float inv = 1.0f / (l0 * e0 + l1 * e1);
#pragma unroll
      for (int n = 0; n < 8; ++n) {
        int col = n * 16 + l15;
        float a0 = bf2f(opart[(size_t)row * HID + h * HD + col]);
        float a1 = bf2f(opart[4194304 + (size_t)row * HID + h * HD + col]);
        float at = (a0 * e0 + a1 * e1) * inv;
        float mem = acc[m][n][r] / den[m][r];
        comb[(size_t)row * HID + h * HD + col] =
            f2bf(gv * mem + (1.0f - gv) * at);
      }
    }
}

// --------------------------- M_new (split-K) --------------------------------
__global__ __launch_bounds__(256) void mnew_part_kernel(
    const short* __restrict__ skT, const short* __restrict__ vT,
    float* __restrict__ part) {
  const int sp = blockIdx.x;
  const int h = blockIdx.y;
  const int tid = threadIdx.x;
  const int wave = tid >> 6, lane = tid & 63;
  const int g = lane >> 4, l15 = lane & 15;
  f32x4 acc[2][8] = {};
  for (int ks = sp * 8; ks < sp * 8 + 8; ++ks) {
    bf16x8 a[2];
#pragma unroll
    for (int m = 0; m < 2; ++m) {
      int dd = wave * 32 + m * 16 + l15;
      a[m] = *reinterpret_cast<const bf16x8*>(skT + (size_t)(h * HD + dd) * S_LEN +
                                              ks * 32 + g * 8);
    }
#pragma unroll
    for (int n = 0; n < 8; ++n) {
      int e = n * 16 + l15;
      bf16x8 b = *reinterpret_cast<const bf16x8*>(
          vT + (size_t)(h * HD + e) * S_LEN + ks * 32 + g * 8);
#pragma unroll
      for (int m = 0; m < 2; ++m)
        acc[m][n] =
            __builtin_amdgcn_mfma_f32_16x16x32_bf16(a[m], b, acc[m][n], 0, 0, 0);
    }
  }
#pragma unroll
  for (int m = 0; m < 2; ++m)
#pragma unroll
    for (int n = 0; n < 8; ++n)
#pragma unroll
      for (int r = 0; r < 4; ++r) {
        int dd = wave * 32 + m * 16 + g * 4 + r;
        int e = n * 16 + l15;
        part[(size_t)(sp * 16 + h) * 16384 + (size_t)dd * 128 + e] =
            acc[m][n][r];
      }
}

__global__ __launch_bounds__(256) void mnew_reduce_kernel(
    const float* __restrict__ part, const float* __restrict__ Mold,
    float* __restrict__ Mout) {
  int idx = blockIdx.x * 256 + threadIdx.x;
  int j4 = idx * 4;
  int h = j4 >> 14;
  int rem = j4 & 16383;
  float4 a = *reinterpret_cast<const float4*>(Mold + j4);
#pragma unroll
  for (int s = 0; s < 8; ++s) {
    float4 p = *reinterpret_cast<const float4*>(
        part + ((size_t)(s * 16 + h) << 14) + rem);
    a.x += p.x;
    a.y += p.y;
    a.z += p.z;
    a.w += p.w;
  }
  *reinterpret_cast<float4*>(Mout + j4) = a;
}

// --------------------------- z_new -----------------------------------------
__global__ __launch_bounds__(256) void znew_kernel(const short* __restrict__ skT,
                                                   const float* __restrict__ z,
                                                   float* __restrict__ out) {
  int row = blockIdx.x;
  int tid = threadIdx.x;
  bf16x8 vv = *reinterpret_cast<const bf16x8*>(skT + (size_t)row * S_LEN + tid * 8);
  float s = 0.0f;
#pragma unroll
  for (int j = 0; j < 8; ++j) s += bf2f(vv[j]);
#pragma unroll
  for (int off = 1; off < 64; off <<= 1) s += __shfl_xor(s, off);
  __shared__ float wsum[4];
  if ((tid & 63) == 0) wsum[tid >> 6] = s;
  __syncthreads();
  if (tid == 0) out[row] = z[row] + wsum[0] + wsum[1] + wsum[2] + wsum[3];
}

// ---------------------------------------------------------------------------
extern "C" void kernel_launch(void* const* d_in, const int* in_sizes, int n_in,
                              void* d_out, int out_size, void* d_ws,
                              size_t ws_size, hipStream_t stream) {
  const float* hs = (const float*)d_in[0];
  const int* pos = (const int*)d_in[2];
  const float* Wq = (const float*)d_in[3];
  const float* bq = (const float*)d_in[4];
  const float* Wk = (const float*)d_in[5];
  const float* bk = (const float*)d_in[6];
  const float* Wo = (const float*)d_in[7];
  const float* beta = (const float*)d_in[8];
  const float* Mm = (const float*)d_in[9];
  const float* z = (const float*)d_in[10];
  float* out = (float*)d_out;

  char* ws = (char*)d_ws;
  const size_t MB = 1u << 20;
  short* hs_b = (short*)(ws + 0);          // 8MB (dead after qk)
  short* WqkT = (short*)(ws + 8 * MB);     // 16MB (dead after qk)
  short* WoT = (short*)(ws + 24 * MB);     // 8MB
  short* qr = (short*)(ws + 32 * MB);      // 8MB
  short* kr = (short*)(ws + 40 * MB);      // 8MB
  short* sq = (short*)(ws + 48 * MB);      // 8MB
  short* skT = (short*)(ws + 56 * MB);     // 8MB
  short* vT = (short*)(ws + 64 * MB);      // 8MB
  short* comb = (short*)(ws + 72 * MB);    // 8MB
  short* MT = (short*)(ws + 80 * MB);      // 512KB
  float* cost = (float*)(ws + 80 * MB + 512 * 1024);  // 512KB
  float* sint = (float*)(ws + 81 * MB);               // 512KB
  // aliases (lifetime-checked):
  short* opart = hs_b;            // 16MB over hs_b+WqT-half (dead after qk)
  float* ml = (float*)(ws + 16 * MB);      // 512KB in dead WkT region
  float* mpart = (float*)(ws + 0);         // 8MB (opart dead after combine)

  f32_to_bf16_kernel<<<2048, 256, 0, stream>>>(hs, hs_b);
  transpose_f2b_kernel<<<dim3(64, 64, 1), 256, 0, stream>>>(Wq, WqkT, 2048, 2048);
  transpose_f2b_kernel<<<dim3(64, 64, 1), 256, 0, stream>>>(
      Wk, WqkT + 4 * 1024 * 1024, 2048, 2048);
  transpose_f2b_kernel<<<dim3(64, 64, 1), 256, 0, stream>>>(Wo, WoT, 2048, 2048);
  transpose_f2b_kernel<<<dim3(4, 4, 16), 256, 0, stream>>>(Mm, MT, 128, 128);
  tables_kernel<<<512, 256, 0, stream>>>(pos, cost, sint);

  gemm_qk_rope_kernel<<<dim3(16, 32), 256, 0, stream>>>(
      hs_b, WqkT, bq, bk, cost, sint, qr, kr, sq, skT, vT);

  attn_kernel<<<512, 512, 0, stream>>>(qr, kr, vT, opart, ml);
  combine_kernel<<<dim3(16, 16), 256, 0, stream>>>(opart, ml, sq, MT, z, beta,
                                                   comb);
  gemm_wo_kernel<<<dim3(16, 16), 256, 0, stream>>>(comb, WoT, out);
  mnew_part_kernel<<<dim3(8, 16), 256, 0, stream>>>(skT, vT, mpart);
  mnew_reduce_kernel<<<256, 256, 0, stream>>>(mpart, Mm, out + 4194304);
  znew_kernel<<<2048, 256, 0, stream>>>(skT, z, out + 4194304 + 16 * 128 * 128);
}